// Round 13
// baseline (126.054 us; speedup 1.0000x reference)
//
#include <hip/hip_runtime.h>
#include <hip/hip_bf16.h>
#include <cstdint>
#include <cmath>

#define EPSV 1e-6f
#define PSTR 1183744

typedef __attribute__((ext_vector_type(8))) short bf16x8;
typedef __attribute__((ext_vector_type(4))) float f32x4;

typedef __attribute__((address_space(3))) unsigned int lds_u32;
typedef const __attribute__((address_space(1))) unsigned int g_u32;

__device__ __forceinline__ void load_lds16(const void* g, void* l) {
  // DMA 16B/lane; LDS dest = wave-uniform base + lane*16 (linear)
  __builtin_amdgcn_global_load_lds((g_u32*)g, (lds_u32*)l, 16, 0, 0);
}

__device__ __forceinline__ short f2b(float f) {
  unsigned u = __float_as_uint(f);
  u = (u + 0x7fffu + ((u >> 16) & 1u)) >> 16;   // RNE fp32 -> bf16
  return (short)u;
}

__device__ __forceinline__ bf16x8 cvt8(float4 a, float4 b) {
  bf16x8 v;
  v[0]=f2b(a.x); v[1]=f2b(a.y); v[2]=f2b(a.z); v[3]=f2b(a.w);
  v[4]=f2b(b.x); v[5]=f2b(b.y); v[6]=f2b(b.z); v[7]=f2b(b.w);
  return v;
}

__global__ __launch_bounds__(256) void conv_bf16(
    const float* __restrict__ in, short* __restrict__ out, int n8) {
  const int i = blockIdx.x * 256 + threadIdx.x;
  if (i < n8) {
    float4 a = ((const float4*)in)[2 * i];
    float4 b = ((const float4*)in)[2 * i + 1];
    ((bf16x8*)out)[i] = cvt8(a, b);
  }
}

// Outp[ks][64][N] = Abf[64,K-slice] @ W[N,K-slice]^T  (bf16 MFMA)
// Small-tile deep-DMA pipeline: 32N x 32K tiles, 3 LDS buffers of
// (4KB W fp32 + 4KB A bf16) = 24 KB total -> 6 blocks/CU, entire grid
// resident in ONE generation (the R11 limiter: 72KB -> 2 blocks/CU,
// 2.26 generations). Stage = exactly 2 global_load_lds per thread;
// ledger: prologue 4 -> vmcnt(2) steady -> vmcnt(0) tail only.
// 48 KB DMA outstanding/CU across 6 INDEPENDENT blocks covers the
// per-wave vmcnt stalls. Zero VGPR global loads in the K-loop.
// XOR-swizzle via pre-swizzled GLOBAL source (rule 21): W ^(r&7)
// on 8 granules/row, A ^(r&3) on 4 granules/row.
template<int KSPLIT, int NT>
__global__ __launch_bounds__(256, 6) void gemm_t32(
    const short* __restrict__ Abf, const float* __restrict__ W,
    float* __restrict__ Outp, int N, int K) {
  __shared__ float Wlds[3][32 * 32];   // [buf][row][32 k fp32]  (4 KB)
  __shared__ short Alds[3][64 * 32];   // [buf][row][32 k bf16]  (4 KB)
  const int tid = threadIdx.x;
  const int lane = tid & 63;
  const int wv = tid >> 6;
  const int lrow = lane & 15, lk = lane >> 4;
  const int bid = blockIdx.x;
  const int ks = bid % KSPLIT;
  const int nblk = (bid / KSPLIT) * 32;
  const int kbase = ks * (NT * 32);

  f32x4 acc[2];
  acc[0] = (f32x4){0.f, 0.f, 0.f, 0.f};
  acc[1] = (f32x4){0.f, 0.f, 0.f, 0.f};

  auto stage = [&](int buf, int k0) {
    // W: 1 instr/thread; wave wv covers rows 8wv..8wv+7 (8 x 128B)
    {
      const int r = wv * 8 + (lane >> 3);
      const int g = (lane & 7) ^ (r & 7);        // pre-swizzled src granule
      load_lds16(W + (size_t)(nblk + r) * K + k0 + g * 4,
                 (char*)&Wlds[buf][0] + wv * 1024);
    }
    // A: 1 instr/thread; wave wv covers rows 16wv..16wv+15 (16 x 64B)
    {
      const int r = wv * 16 + (lane >> 2);
      const int g = (lane & 3) ^ (r & 3);
      load_lds16(Abf + (size_t)r * K + k0 + g * 8,
                 (char*)&Alds[buf][0] + wv * 1024);
    }
  };

  auto compute = [&](int buf) {
    const int rn = (wv & 1) * 16 + lrow;         // W local row
    const float4 wlo = *(const float4*)((const char*)&Wlds[buf][0]
                        + rn * 128 + (((2 * lk)     ^ (rn & 7)) * 16));
    const float4 whi = *(const float4*)((const char*)&Wlds[buf][0]
                        + rn * 128 + (((2 * lk + 1) ^ (rn & 7)) * 16));
    const bf16x8 wb = cvt8(wlo, whi);
#pragma unroll
    for (int mf = 0; mf < 2; ++mf) {
      const int ar = (wv >> 1) * 32 + mf * 16 + lrow;
      const bf16x8 av = *(const bf16x8*)((const char*)&Alds[buf][0]
                         + ar * 64 + ((lk ^ (ar & 3)) * 16));
      acc[mf] = __builtin_amdgcn_mfma_f32_16x16x32_bf16(av, wb, acc[mf], 0, 0, 0);
    }
  };

  // prologue: 2 tiles in flight = 4 loads/thread outstanding
  stage(0, kbase);
  stage(1, kbase + 32);

  for (int t = 0; t < NT; ++t) {
    if (t < NT - 1) asm volatile("s_waitcnt vmcnt(2)" ::: "memory");
    else            asm volatile("s_waitcnt vmcnt(0)" ::: "memory");
    __builtin_amdgcn_sched_barrier(0);
    __builtin_amdgcn_s_barrier();     // tile t visible; all waves done compute(t-1)
    __builtin_amdgcn_sched_barrier(0);
    compute(t % 3);
    if (t + 2 <= NT - 1) stage((t + 2) % 3, kbase + (t + 2) * 32);
  }

  // C/D layout: col(lane&15)=n, row=(lane>>4)*4+i=m  [m89-verified]
  float* ob = Outp + (size_t)ks * 64 * N + nblk + (wv & 1) * 16 + lrow;
#pragma unroll
  for (int mf = 0; mf < 2; ++mf)
#pragma unroll
    for (int i = 0; i < 4; ++i)
      ob[(size_t)((wv >> 1) * 32 + mf * 16 + lk * 4 + i) * N] = acc[mf][i];
}

__device__ __forceinline__ float block_reduce_sum256(float v, float* red, int t) {
#pragma unroll
  for (int o = 32; o > 0; o >>= 1) v += __shfl_xor(v, o, 64);
  __syncthreads();
  if ((t & 63) == 0) red[t >> 6] = v;
  __syncthreads();
  return red[0] + red[1] + red[2] + red[3];
}

// one block per (b, head); 256 threads. proj = pp0 + pp1 (split-K partials).
__global__ __launch_bounds__(256) void state_update(
    const float* __restrict__ pp0, const float* __restrict__ pp1,
    const float* __restrict__ h,
    const float* __restrict__ B_prev, const float* __restrict__ x_prev,
    const float* __restrict__ theta_cumsum, const float* __restrict__ A_log,
    const float* __restrict__ B_bias, const float* __restrict__ C_bias,
    float* __restrict__ o_h, float* __restrict__ o_B,
    float* __restrict__ o_xp, float* __restrict__ o_th,
    short* __restrict__ ysbf) {
  const int bid = blockIdx.x;            // b*32 + hd
  const int b = bid >> 5, hd = bid & 31;
  const int t = threadIdx.x;
  const size_t pb = (size_t)b * 18496;
#define PJ(o) (pp0[pb + (o)] + pp1[pb + (o)])

  __shared__ float sB[128], sC[128], sBp[128], sXp[128], sXv[128];
  __shared__ float red[8];
  __shared__ float yred[8][128];

  float aval = (t < 128) ? expf(A_log[hd * 128 + t]) : 0.f;
  float brv  = (t < 128) ? PJ(8192 + hd * 128 + t) : 0.f;
  float crv  = (t < 128) ? PJ(12288 + hd * 128 + t) : 0.f;
  if (t < 128) {
    sBp[t] = B_prev[(size_t)bid * 128 + t];
    float xp = PJ(hd * 128 + t);
    sXp[t] = xp;
    o_xp[(size_t)bid * 128 + t] = xp;
    sXv[t] = x_prev[(size_t)bid * 128 + t];
  }
  float sumA  = block_reduce_sum256(aval, red, t);
  float sumB2 = block_reduce_sum256(brv * brv, red, t);
  float sumC2 = block_reduce_sum256(crv * crv, red, t);

  const float dt_raw  = PJ(16384 + hd);
  const float lam_raw = PJ(16416 + hd);
  const float dt  = (dt_raw > 20.f) ? dt_raw : log1pf(expf(dt_raw));
  const float lam = 1.f / (1.f + expf(-lam_raw));
  const float A     = -sumA * (1.f / 128.f);
  const float alpha = expf(dt * A);
  const float beta  = (1.f - lam) * dt * alpha;
  const float gamma = lam * dt;
  const float rb = rsqrtf(sumB2 * (1.f / 128.f) + EPSV);
  const float rc = rsqrtf(sumC2 * (1.f / 128.f) + EPSV);

  if (t < 64) {
    float b0 = PJ(8192 + hd * 128 + 2 * t);
    float b1 = PJ(8192 + hd * 128 + 2 * t + 1);
    float c0 = PJ(12288 + hd * 128 + 2 * t);
    float c1 = PJ(12288 + hd * 128 + 2 * t + 1);
    b0 = b0 * rb + B_bias[hd * 128 + 2 * t];
    b1 = b1 * rb + B_bias[hd * 128 + 2 * t + 1];
    c0 = c0 * rc + C_bias[hd * 128 + 2 * t];
    c1 = c1 * rc + C_bias[hd * 128 + 2 * t + 1];
    const float th = theta_cumsum[(size_t)bid * 64 + t]
                   + PJ(16448 + hd * 64 + t) * dt;
    o_th[(size_t)bid * 64 + t] = th;
    const float cth = cosf(th), sth = sinf(th);
    const float nb0 = b0 * cth - b1 * sth, nb1 = b0 * sth + b1 * cth;
    const float nc0 = c0 * cth - c1 * sth, nc1 = c0 * sth + c1 * cth;
    sB[2 * t] = nb0; sB[2 * t + 1] = nb1;
    sC[2 * t] = nc0; sC[2 * t + 1] = nc1;
    o_B[(size_t)bid * 128 + 2 * t] = nb0;
    o_B[(size_t)bid * 128 + 2 * t + 1] = nb1;
  }
  __syncthreads();

  const int p4 = t & 31, nb = t >> 5;
  const float4 xp4 = *(const float4*)&sXp[p4 * 4];
  const float4 xv4 = *(const float4*)&sXv[p4 * 4];
  const size_t hbase = (size_t)bid * 16384;
  float4 ya = {0.f, 0.f, 0.f, 0.f};
#pragma unroll 4
  for (int n = nb; n < 128; n += 8) {
    const float4 hv = *(const float4*)&h[hbase + n * 128 + p4 * 4];
    const float cb = gamma * sB[n];
    const float cp = beta * sBp[n];
    float4 hn;
    hn.x = alpha * hv.x + cp * xv4.x + cb * xp4.x;
    hn.y = alpha * hv.y + cp * xv4.y + cb * xp4.y;
    hn.z = alpha * hv.z + cp * xv4.z + cb * xp4.z;
    hn.w = alpha * hv.w + cp * xv4.w + cb * xp4.w;
    *(float4*)&o_h[hbase + n * 128 + p4 * 4] = hn;
    const float cn = sC[n];
    ya.x += cn * hn.x; ya.y += cn * hn.y; ya.z += cn * hn.z; ya.w += cn * hn.w;
  }
  *(float4*)&yred[nb][p4 * 4] = ya;
  __syncthreads();
  if (t < 128) {
    float y = 0.f;
#pragma unroll
    for (int j = 0; j < 8; ++j) y += yred[j][t];
    const float zv = PJ(4096 + hd * 128 + t);
    const float sig = 1.f / (1.f + expf(-zv));
    ysbf[(size_t)b * 4096 + hd * 128 + t] = f2b(y * zv * sig);
  }
#undef PJ
}

// y[64][2048] = sum over 8 K-split partials
__global__ __launch_bounds__(256) void reduce_y(
    const float* __restrict__ yp, float* __restrict__ y, int n4) {
  const int i = blockIdx.x * 256 + threadIdx.x;
  if (i < n4) {
    float4 s = ((const float4*)yp)[i];
#pragma unroll
    for (int k = 1; k < 8; ++k) {
      float4 t = ((const float4*)(yp + (size_t)k * 131072))[i];
      s.x += t.x; s.y += t.y; s.z += t.z; s.w += t.w;
    }
    ((float4*)y)[i] = s;
  }
}

extern "C" void kernel_launch(void* const* d_in, const int* in_sizes, int n_in,
                              void* d_out, int out_size, void* d_ws, size_t ws_size,
                              hipStream_t stream) {
  const float* x            = (const float*)d_in[0];
  const float* h            = (const float*)d_in[1];
  const float* B_prev       = (const float*)d_in[2];
  const float* x_prev       = (const float*)d_in[3];
  const float* theta_cumsum = (const float*)d_in[4];
  const float* W_in         = (const float*)d_in[5];
  const float* A_log        = (const float*)d_in[6];
  const float* B_bias       = (const float*)d_in[7];
  const float* C_bias       = (const float*)d_in[8];
  const float* W_out        = (const float*)d_in[9];

  float* out  = (float*)d_out;
  float* o_y  = out;                        // 64*2048
  float* o_h  = out + 131072;               // 64*32*128*128
  float* o_B  = o_h + 33554432;             // 64*32*128
  float* o_xp = o_B + 262144;               // 64*32*128
  float* o_th = o_xp + 262144;              // 64*32*64

  // ws layout
  float* pp   = (float*)d_ws;               // 2 x PSTR fp32 split-K partials
  float* yp   = pp;                         // 8 x 131072 fp32 (reuse after SU)
  short* xbf  = (short*)(pp + 2 * PSTR);    // 64*2048 bf16
  short* ysbf = xbf + 131072;               // 64*4096 bf16

  // 1) x -> bf16
  conv_bf16<<<dim3(64), dim3(256), 0, stream>>>(x, xbf, 16384);
  // 2) proj partials = xbf @ W_in^T  (N=18496, K=2048, KSPLIT=2, NT=32)
  //    578 strips x 2 = 1156 blocks @ 24KB LDS -> 6/CU, single generation
  gemm_t32<2, 32><<<dim3(578 * 2), dim3(256), 0, stream>>>(
      xbf, W_in, pp, 18496, 2048);
  // 3) fused state update (sums 2 partials at load)
  state_update<<<dim3(2048), dim3(256), 0, stream>>>(
      pp, pp + PSTR, h, B_prev, x_prev, theta_cumsum, A_log, B_bias, C_bias,
      o_h, o_B, o_xp, o_th, ysbf);
  // 4) y partials = ysbf @ W_out^T   (N=2048, K=4096, KSPLIT=8, NT=16)
  gemm_t32<8, 16><<<dim3(64 * 8), dim3(256), 0, stream>>>(
      ysbf, W_out, yp, 2048, 4096);
  // 5) final y reduce
  reduce_y<<<dim3(128), dim3(256), 0, stream>>>(yp, o_y, 32768);
}